// Round 1
// baseline (695.380 us; speedup 1.0000x reference)
//
#include <hip/hip_runtime.h>

// Greedy CTC decode: T=1048576 rows, V=128 labels, blank=0.
// Outputs concatenated float32 in d_out: [idx as float | keep as 0/1 float | path_score]
//
// Pass 1: per-thread row argmax+max (memory-bound, 512 MB read).
// Pass 2: run-length dedup vs previous idx (needs cross-block neighbor -> separate pass).

#define VLAB 128

__global__ void ctc_pass1(const float* __restrict__ em,
                          int* __restrict__ idx_ws,
                          float* __restrict__ max_ws,
                          float* __restrict__ out_idx,
                          int T) {
    int t = blockIdx.x * blockDim.x + threadIdx.x;
    if (t >= T) return;
    const float4* row = reinterpret_cast<const float4*>(em) + (size_t)t * (VLAB / 4);
    float best = -3.402823466e38f;
    int bidx = 0;
    // Strictly-greater keeps the FIRST occurrence of the max -> matches jnp.argmax.
    #pragma unroll
    for (int k = 0; k < VLAB / 4; ++k) {
        float4 v = row[k];
        if (v.x > best) { best = v.x; bidx = 4 * k + 0; }
        if (v.y > best) { best = v.y; bidx = 4 * k + 1; }
        if (v.z > best) { best = v.z; bidx = 4 * k + 2; }
        if (v.w > best) { best = v.w; bidx = 4 * k + 3; }
    }
    idx_ws[t] = bidx;
    max_ws[t] = best;
    out_idx[t] = (float)bidx;
}

__global__ void ctc_pass2(const int* __restrict__ idx_ws,
                          const float* __restrict__ max_ws,
                          float* __restrict__ out_keep,
                          float* __restrict__ out_score,
                          int T) {
    int t = blockIdx.x * blockDim.x + threadIdx.x;
    if (t >= T) return;
    int cur = idx_ws[t];
    int prev = (t == 0) ? -1 : idx_ws[t - 1];
    bool keep = (cur != prev) && (cur != 0);
    out_keep[t]  = keep ? 1.0f : 0.0f;
    out_score[t] = keep ? max_ws[t] : 0.0f;
}

extern "C" void kernel_launch(void* const* d_in, const int* in_sizes, int n_in,
                              void* d_out, int out_size, void* d_ws, size_t ws_size,
                              hipStream_t stream) {
    const float* em = (const float*)d_in[0];
    const int T = in_sizes[0] / VLAB;

    float* out       = (float*)d_out;
    float* out_idx   = out;
    float* out_keep  = out + (size_t)T;
    float* out_score = out + (size_t)2 * T;

    int*   idx_ws = (int*)d_ws;
    float* max_ws = (float*)((char*)d_ws + (size_t)T * sizeof(int));

    const int block = 256;
    const int grid = (T + block - 1) / block;
    ctc_pass1<<<grid, block, 0, stream>>>(em, idx_ws, max_ws, out_idx, T);
    ctc_pass2<<<grid, block, 0, stream>>>(idx_ws, max_ws, out_keep, out_score, T);
}

// Round 2
// 685.106 us; speedup vs baseline: 1.0150x; 1.0150x over previous
//
#include <hip/hip_runtime.h>

// Greedy CTC decode: T=1048576 rows, V=128 labels (512 B/row), blank=0.
// Outputs concatenated float32 in d_out: [idx | keep(0/1) | path_score].
//
// Wave-cooperative: one float4/lane -> one wave-load covers 2 full rows,
// perfectly coalesced (1 KB contiguous). Shuffle-xor argmax within each
// 32-lane half. Block = 256 threads = 4 waves = 256 rows (8 iters x 8 rows/wave).
// Row base-1 is recomputed by wave 0 (0.4% redundant read) so dedup fuses in.

#define VLAB 128
#define ROWS_PER_BLOCK 256

__device__ __forceinline__ void argmax4(const float4 v, int l, float& best, int& idx) {
    best = v.x; idx = l * 4;
    if (v.y > best) { best = v.y; idx = l * 4 + 1; }
    if (v.z > best) { best = v.z; idx = l * 4 + 2; }
    if (v.w > best) { best = v.w; idx = l * 4 + 3; }
}

__global__ __launch_bounds__(256) void ctc_fused(const float4* __restrict__ em4,
                                                 float* __restrict__ out_idx,
                                                 float* __restrict__ out_keep,
                                                 float* __restrict__ out_score) {
    __shared__ int   s_idx[ROWS_PER_BLOCK + 1];
    __shared__ float s_max[ROWS_PER_BLOCK + 1];

    const int tid  = threadIdx.x;
    const int wave = tid >> 6;
    const int lane = tid & 63;
    const int half = lane >> 5;   // which row of the pair this lane reduces
    const int l    = lane & 31;   // lane within the 32-lane half
    const int base = blockIdx.x * ROWS_PER_BLOCK;

    // 8 iterations; each wave handles 4 row-pairs (8 rows) per iteration.
    #pragma unroll
    for (int i = 0; i < 8; ++i) {
        const int r0 = base + i * 32 + wave * 8;
        float4 v4[4];
        #pragma unroll
        for (int j = 0; j < 4; ++j) {
            // lanes 0-31 -> row r0+2j, lanes 32-63 -> row r0+2j+1 (contiguous 1 KB)
            v4[j] = em4[(size_t)(r0 + 2 * j) * 32 + lane];
        }
        float bv[4]; int bi[4];
        #pragma unroll
        for (int j = 0; j < 4; ++j) argmax4(v4[j], l, bv[j], bi[j]);

        #pragma unroll
        for (int m = 16; m >= 1; m >>= 1) {
            #pragma unroll
            for (int j = 0; j < 4; ++j) {
                float ov = __shfl_xor(bv[j], m, 32);
                int   oi = __shfl_xor(bi[j], m, 32);
                // prefer larger value; on tie, lower index (jnp.argmax semantics)
                if (ov > bv[j] || (ov == bv[j] && oi < bi[j])) { bv[j] = ov; bi[j] = oi; }
            }
        }
        if (l == 0) {
            #pragma unroll
            for (int j = 0; j < 4; ++j) {
                int slot = (r0 - base) + 2 * j + half + 1;
                s_idx[slot] = bi[j];
                s_max[slot] = bv[j];
            }
        }
    }

    // Row base-1 (for the dedup boundary), recomputed by wave 0.
    if (wave == 0) {
        if (blockIdx.x > 0) {
            // lanes 0-31 -> row base-1; lanes 32-63 redundantly read row base.
            float4 v = em4[(size_t)(base - 1) * 32 + lane];
            float best; int idx;
            argmax4(v, l, best, idx);
            #pragma unroll
            for (int m = 16; m >= 1; m >>= 1) {
                float ov = __shfl_xor(best, m, 32);
                int   oi = __shfl_xor(idx, m, 32);
                if (ov > best || (ov == best && oi < idx)) { best = ov; idx = oi; }
            }
            if (lane == 0) s_idx[0] = idx;
        } else if (tid == 0) {
            s_idx[0] = -1;  // prev of row 0
        }
    }

    __syncthreads();

    // Coalesced epilogue: one row per thread.
    const int r   = base + tid;
    const int cur = s_idx[tid + 1];
    const int prv = s_idx[tid];
    const bool keep = (cur != prv) && (cur != 0);
    out_idx[r]   = (float)cur;
    out_keep[r]  = keep ? 1.0f : 0.0f;
    out_score[r] = keep ? s_max[tid + 1] : 0.0f;
}

extern "C" void kernel_launch(void* const* d_in, const int* in_sizes, int n_in,
                              void* d_out, int out_size, void* d_ws, size_t ws_size,
                              hipStream_t stream) {
    const float* em = (const float*)d_in[0];
    const int T = in_sizes[0] / VLAB;

    float* out       = (float*)d_out;
    float* out_idx   = out;
    float* out_keep  = out + (size_t)T;
    float* out_score = out + (size_t)2 * T;

    const int grid = T / ROWS_PER_BLOCK;  // T = 1048576 -> 4096 blocks
    ctc_fused<<<grid, ROWS_PER_BLOCK, 0, stream>>>(
        reinterpret_cast<const float4*>(em), out_idx, out_keep, out_score);
}

// Round 3
// 674.612 us; speedup vs baseline: 1.0308x; 1.0156x over previous
//
#include <hip/hip_runtime.h>

// Greedy CTC decode: T=1048576 rows, V=128 labels (512 B/row), blank=0.
// Outputs concatenated float32 in d_out: [idx | keep(0/1) | path_score].
//
// 8 lanes per row: each lane privately argmaxes 16 elems (4 x float4, VALU),
// then 3 shfl_xor rounds (masks 1/2/4) finish the row -> 6 DS ops per 8 rows
// (vs 40 in the 32-lane variant). Each 8-lane group's load = one full 128 B
// line; all lines fully consumed -> coalescing preserved, ~524 MB total HBM.
// Block = 256 threads = 4 waves = 256 rows. Row base-1 recomputed by wave 0
// so run-length dedup fuses into the same kernel.

#define VLAB 128
#define ROWS_PER_BLOCK 256

__device__ __forceinline__ void upd(float v, int c, float& bv, int& bi) {
    if (v > bv) { bv = v; bi = c; }
}

// Lane-local argmax of 16 elems; cols = 4g+{0..3}, 4g+32+{0..3}, 4g+64+.., 4g+96+..
// Scanned in ascending column order with strict > -> first-max wins locally.
__device__ __forceinline__ void local_argmax(const float4 v0, const float4 v1,
                                             const float4 v2, const float4 v3,
                                             int g, float& bv, int& bi) {
    bv = v0.x; bi = 4 * g;
    upd(v0.y, 4*g + 1, bv, bi);  upd(v0.z, 4*g + 2, bv, bi);  upd(v0.w, 4*g + 3, bv, bi);
    upd(v1.x, 4*g + 32, bv, bi); upd(v1.y, 4*g + 33, bv, bi);
    upd(v1.z, 4*g + 34, bv, bi); upd(v1.w, 4*g + 35, bv, bi);
    upd(v2.x, 4*g + 64, bv, bi); upd(v2.y, 4*g + 65, bv, bi);
    upd(v2.z, 4*g + 66, bv, bi); upd(v2.w, 4*g + 67, bv, bi);
    upd(v3.x, 4*g + 96, bv, bi); upd(v3.y, 4*g + 97, bv, bi);
    upd(v3.z, 4*g + 98, bv, bi); upd(v3.w, 4*g + 99, bv, bi);
}

__global__ __launch_bounds__(256) void ctc_fused(const float4* __restrict__ em4,
                                                 float* __restrict__ out_idx,
                                                 float* __restrict__ out_keep,
                                                 float* __restrict__ out_score) {
    __shared__ int   s_idx[ROWS_PER_BLOCK + 1];
    __shared__ float s_max[ROWS_PER_BLOCK + 1];

    const int tid  = threadIdx.x;
    const int wave = tid >> 6;
    const int lane = tid & 63;
    const int g    = lane & 7;    // lane within 8-lane row group
    const int rsub = lane >> 3;   // row within this wave-iteration (0..7)
    const int base = blockIdx.x * ROWS_PER_BLOCK;

    // 8 iterations; each wave reduces 8 rows per iteration (64 rows/wave).
    #pragma unroll
    for (int i = 0; i < 8; ++i) {
        const int row = base + i * 32 + wave * 8 + rsub;
        const float4* rp = em4 + (size_t)row * 32 + g;
        const float4 v0 = rp[0], v1 = rp[8], v2 = rp[16], v3 = rp[24];

        float bv; int bi;
        local_argmax(v0, v1, v2, v3, g, bv, bi);

        // Cross-lane over the 8-lane group; tie-break on true column index.
        #pragma unroll
        for (int m = 1; m <= 4; m <<= 1) {
            float ov = __shfl_xor(bv, m, 64);
            int   oi = __shfl_xor(bi, m, 64);
            if (ov > bv || (ov == bv && oi < bi)) { bv = ov; bi = oi; }
        }
        if (g == 0) {
            s_idx[row - base + 1] = bi;
            s_max[row - base + 1] = bv;
        }
    }

    // Row base-1 for the dedup boundary (wave 0; all 8-lane groups redundant).
    if (wave == 0) {
        if (blockIdx.x > 0) {
            const float4* rp = em4 + (size_t)(base - 1) * 32 + g;
            const float4 v0 = rp[0], v1 = rp[8], v2 = rp[16], v3 = rp[24];
            float bv; int bi;
            local_argmax(v0, v1, v2, v3, g, bv, bi);
            #pragma unroll
            for (int m = 1; m <= 4; m <<= 1) {
                float ov = __shfl_xor(bv, m, 64);
                int   oi = __shfl_xor(bi, m, 64);
                if (ov > bv || (ov == bv && oi < bi)) { bv = ov; bi = oi; }
            }
            if (lane == 0) s_idx[0] = bi;
        } else if (tid == 0) {
            s_idx[0] = -1;  // prev of row 0
        }
    }

    __syncthreads();

    // Coalesced epilogue: one row per thread.
    const int r   = base + tid;
    const int cur = s_idx[tid + 1];
    const int prv = s_idx[tid];
    const bool keep = (cur != prv) && (cur != 0);
    out_idx[r]   = (float)cur;
    out_keep[r]  = keep ? 1.0f : 0.0f;
    out_score[r] = keep ? s_max[tid + 1] : 0.0f;
}

extern "C" void kernel_launch(void* const* d_in, const int* in_sizes, int n_in,
                              void* d_out, int out_size, void* d_ws, size_t ws_size,
                              hipStream_t stream) {
    const float* em = (const float*)d_in[0];
    const int T = in_sizes[0] / VLAB;

    float* out       = (float*)d_out;
    float* out_idx   = out;
    float* out_keep  = out + (size_t)T;
    float* out_score = out + (size_t)2 * T;

    const int grid = T / ROWS_PER_BLOCK;  // 4096 blocks
    ctc_fused<<<grid, ROWS_PER_BLOCK, 0, stream>>>(
        reinterpret_cast<const float4*>(em), out_idx, out_keep, out_score);
}

// Round 4
// 674.480 us; speedup vs baseline: 1.0310x; 1.0002x over previous
//
#include <hip/hip_runtime.h>

// Greedy CTC decode: T=1048576 rows, V=128 labels (512 B/row), blank=0.
// Outputs concatenated float32 in d_out: [idx | keep(0/1) | path_score].
//
// 8 lanes/row, 3 shfl_xor rounds per row. Explicit 2-stage register
// double-buffer: iteration i+1's 4 loads issue BEFORE iteration i's
// reduce/shuffle/LDS tail, so vmcnt never drains inside the loop.
// Boundary row (base-1) loads issue at kernel entry and are consumed at
// the end -> latency overlapped. Block = 256 thr = 4 waves = 256 rows.

#define VLAB 128
#define RPB 256

__device__ __forceinline__ void upd(float v, int c, float& bv, int& bi) {
    if (v > bv) { bv = v; bi = c; }
}

// Lane-local argmax of 16 elems, ascending column order (first-max wins).
__device__ __forceinline__ void local_argmax(const float4* v, int g,
                                             float& bv, int& bi) {
    bv = v[0].x; bi = 4 * g;
    upd(v[0].y, 4*g + 1, bv, bi);  upd(v[0].z, 4*g + 2, bv, bi);  upd(v[0].w, 4*g + 3, bv, bi);
    upd(v[1].x, 4*g + 32, bv, bi); upd(v[1].y, 4*g + 33, bv, bi);
    upd(v[1].z, 4*g + 34, bv, bi); upd(v[1].w, 4*g + 35, bv, bi);
    upd(v[2].x, 4*g + 64, bv, bi); upd(v[2].y, 4*g + 65, bv, bi);
    upd(v[2].z, 4*g + 66, bv, bi); upd(v[2].w, 4*g + 67, bv, bi);
    upd(v[3].x, 4*g + 96, bv, bi); upd(v[3].y, 4*g + 97, bv, bi);
    upd(v[3].z, 4*g + 98, bv, bi); upd(v[3].w, 4*g + 99, bv, bi);
}

__device__ __forceinline__ void group8_reduce(float& bv, int& bi) {
    #pragma unroll
    for (int m = 1; m <= 4; m <<= 1) {
        float ov = __shfl_xor(bv, m, 64);
        int   oi = __shfl_xor(bi, m, 64);
        if (ov > bv || (ov == bv && oi < bi)) { bv = ov; bi = oi; }
    }
}

__global__ __launch_bounds__(256, 6) void ctc_fused(const float4* __restrict__ em4,
                                                    float* __restrict__ out_idx,
                                                    float* __restrict__ out_keep,
                                                    float* __restrict__ out_score) {
    __shared__ int   s_idx[RPB + 1];
    __shared__ float s_max[RPB + 1];

    const int tid  = threadIdx.x;
    const int wave = tid >> 6;
    const int lane = tid & 63;
    const int g    = lane & 7;    // lane within 8-lane row group
    const int rsub = lane >> 3;   // row within wave-iteration (0..7)
    const int base = blockIdx.x * RPB;

    // Boundary row (base-1): issue loads first so they overlap the main loop.
    float4 bb[4];
    const bool do_bnd = (wave == 0) && (blockIdx.x > 0);
    if (do_bnd) {
        const float4* bp = em4 + (size_t)(base - 1) * 32 + g;
        bb[0] = bp[0]; bb[1] = bp[8]; bb[2] = bp[16]; bb[3] = bp[24];
    }

    // Prologue: load iteration 0.
    float4 buf[2][4];
    {
        const float4* rp = em4 + (size_t)(base + wave * 8 + rsub) * 32 + g;
        buf[0][0] = rp[0]; buf[0][1] = rp[8]; buf[0][2] = rp[16]; buf[0][3] = rp[24];
    }

    #pragma unroll
    for (int i = 0; i < 8; ++i) {
        const int cur = i & 1;
        if (i < 7) {
            const int nrow = base + (i + 1) * 32 + wave * 8 + rsub;
            const float4* rp = em4 + (size_t)nrow * 32 + g;
            buf[cur ^ 1][0] = rp[0];  buf[cur ^ 1][1] = rp[8];
            buf[cur ^ 1][2] = rp[16]; buf[cur ^ 1][3] = rp[24];
        }
        float bv; int bi;
        local_argmax(buf[cur], g, bv, bi);
        group8_reduce(bv, bi);
        if (g == 0) {
            const int slot = i * 32 + wave * 8 + rsub + 1;
            s_idx[slot] = bi;
            s_max[slot] = bv;
        }
    }

    // Consume the boundary row.
    if (do_bnd) {
        float bv; int bi;
        local_argmax(bb, g, bv, bi);
        group8_reduce(bv, bi);
        if (lane == 0) s_idx[0] = bi;
    } else if (blockIdx.x == 0 && tid == 0) {
        s_idx[0] = -1;  // prev of row 0
    }

    __syncthreads();

    // Coalesced epilogue: one row per thread.
    const int r   = base + tid;
    const int cur = s_idx[tid + 1];
    const int prv = s_idx[tid];
    const bool keep = (cur != prv) && (cur != 0);
    out_idx[r]   = (float)cur;
    out_keep[r]  = keep ? 1.0f : 0.0f;
    out_score[r] = keep ? s_max[tid + 1] : 0.0f;
}

extern "C" void kernel_launch(void* const* d_in, const int* in_sizes, int n_in,
                              void* d_out, int out_size, void* d_ws, size_t ws_size,
                              hipStream_t stream) {
    const float* em = (const float*)d_in[0];
    const int T = in_sizes[0] / VLAB;

    float* out       = (float*)d_out;
    float* out_idx   = out;
    float* out_keep  = out + (size_t)T;
    float* out_score = out + (size_t)2 * T;

    const int grid = T / RPB;  // 4096 blocks
    ctc_fused<<<grid, RPB, 0, stream>>>(
        reinterpret_cast<const float4*>(em), out_idx, out_keep, out_score);
}